// Round 3
// baseline (847.399 us; speedup 1.0000x reference)
//
#include <hip/hip_runtime.h>
#include <hip/hip_cooperative_groups.h>

namespace cg = cooperative_groups;

#define N_ROWS 1024
#define M_COLS 16384
#define DIM 512

constexpr float GAMMA_ = 0.1f;
constexpr float INV_GAMMA = 10.0f;
constexpr float EPS_ = 0.005f;
constexpr float TINY_ = 1e-30f;
constexpr float RVAL = 1.0f / 1024.0f;
constexpr float CVAL = 1.0f / 16384.0f;

__device__ __forceinline__ float waveRedSum(float v) {
#pragma unroll
    for (int o = 32; o > 0; o >>= 1) v += __shfl_down(v, o);
    return v;
}
__device__ __forceinline__ float waveRedMin(float v) {
#pragma unroll
    for (int o = 32; o > 0; o >>= 1) v = fminf(v, __shfl_down(v, o));
    return v;
}

// ---- hierarchical global barrier: 16 groups x 16 blocks, monotonic epochs ----
// bar layout (uint):
//   [g*16]        g=0..15 : group arrival counters (separate 64B lines)
//   [256 + g*16]  g=0..15 : group epoch flags
//   [512]                 : root arrival counter
//   [528]                 : root epoch flag
__device__ __forceinline__ void gbar(unsigned* __restrict__ bar, int b, int tid, unsigned e) {
    __syncthreads();   // drains vmcnt: block's stores are at L2
    if (tid == 0) {
        __threadfence();   // agent-scope: wb this XCD's L2 so other XCDs can see our writes
        const int g = b & 15;
        unsigned old = __hip_atomic_fetch_add(&bar[g * 16], 1u, __ATOMIC_ACQ_REL, __HIP_MEMORY_SCOPE_AGENT);
        if ((old & 15u) == 15u) {  // 16th arrival in this group for this epoch
            unsigned r = __hip_atomic_fetch_add(&bar[512], 1u, __ATOMIC_ACQ_REL, __HIP_MEMORY_SCOPE_AGENT);
            if ((r & 15u) == 15u) {
                __hip_atomic_store(&bar[528], e, __ATOMIC_RELEASE, __HIP_MEMORY_SCOPE_AGENT);
            } else {
                while (__hip_atomic_load(&bar[528], __ATOMIC_ACQUIRE, __HIP_MEMORY_SCOPE_AGENT) < e)
                    __builtin_amdgcn_s_sleep(1);
            }
            __hip_atomic_store(&bar[256 + g * 16], e, __ATOMIC_RELEASE, __HIP_MEMORY_SCOPE_AGENT);
        } else {
            while (__hip_atomic_load(&bar[256 + g * 16], __ATOMIC_ACQUIRE, __HIP_MEMORY_SCOPE_AGENT) < e)
                __builtin_amdgcn_s_sleep(1);
        }
        __threadfence();   // acquire side: invalidate L1/L2 so we refetch others' data
    }
    __syncthreads();
}

// ---- sq norms: one block (128 thr) per row ----
__global__ void row_sqnorm(const float* __restrict__ X, float* __restrict__ out) {
    int row = blockIdx.x;
    const float* xr = X + (size_t)row * DIM;
    int tid = threadIdx.x;
    float acc = 0.f;
    for (int k = tid; k < DIM; k += 128) { float v = xr[k]; acc = fmaf(v, v, acc); }
    acc = waveRedSum(acc);
    __shared__ float red[2];
    if ((tid & 63) == 0) red[tid >> 6] = acc;
    __syncthreads();
    if (tid == 0) out[row] = red[0] + red[1];
}

// ---- M = sx + sy - 2*X@Y^T  (f32, 128x128 tile, 8x8/thread) ----
__global__ __launch_bounds__(256) void gemm_dist(const float* __restrict__ X, const float* __restrict__ Y,
                                                 const float* __restrict__ sx, const float* __restrict__ sy,
                                                 float* __restrict__ Mout) {
    alignas(16) __shared__ float As[16][132];
    alignas(16) __shared__ float Bs[16][132];
    const int tid = threadIdx.x;
    const int tx = tid & 15, ty = tid >> 4;
    const int row0 = blockIdx.y * 128, col0 = blockIdx.x * 128;
    float acc[8][8] = {};
    for (int k0 = 0; k0 < DIM; k0 += 16) {
#pragma unroll
        for (int p = 0; p < 2; ++p) {
            int idx = tid + (p << 8);
            int r = idx >> 2;
            int kq = (idx & 3) << 2;
            float4 va = *(const float4*)(X + (size_t)(row0 + r) * DIM + k0 + kq);
            As[kq + 0][r] = va.x; As[kq + 1][r] = va.y; As[kq + 2][r] = va.z; As[kq + 3][r] = va.w;
            float4 vb = *(const float4*)(Y + (size_t)(col0 + r) * DIM + k0 + kq);
            Bs[kq + 0][r] = vb.x; Bs[kq + 1][r] = vb.y; Bs[kq + 2][r] = vb.z; Bs[kq + 3][r] = vb.w;
        }
        __syncthreads();
#pragma unroll
        for (int kk = 0; kk < 16; ++kk) {
            float a[8], b[8];
            *(float4*)&a[0] = *(const float4*)&As[kk][ty * 8];
            *(float4*)&a[4] = *(const float4*)&As[kk][ty * 8 + 4];
            *(float4*)&b[0] = *(const float4*)&Bs[kk][tx * 8];
            *(float4*)&b[4] = *(const float4*)&Bs[kk][tx * 8 + 4];
#pragma unroll
            for (int i = 0; i < 8; ++i)
#pragma unroll
                for (int j = 0; j < 8; ++j)
                    acc[i][j] = fmaf(a[i], b[j], acc[i][j]);
        }
        __syncthreads();
    }
#pragma unroll
    for (int i = 0; i < 8; ++i) {
        int gr = row0 + ty * 8 + i;
        float sxi = sx[gr];
        float* orow = Mout + (size_t)gr * M_COLS + col0 + tx * 8;
#pragma unroll
        for (int j = 0; j < 8; ++j) {
            orow[j] = sxi + sy[col0 + tx * 8 + j] - 2.0f * acc[i][j];
        }
    }
}

// ---- row min of M ----
__global__ void row_min(const float* __restrict__ Mb, float* __restrict__ Mmin) {
    int row = blockIdx.x;
    const float* mr = Mb + (size_t)row * M_COLS;
    int tid = threadIdx.x;
    float mn = INFINITY;
    for (int j = tid; j < M_COLS; j += 256) mn = fminf(mn, mr[j]);
    mn = waveRedMin(mn);
    __shared__ float red[4];
    if ((tid & 63) == 0) red[tid >> 6] = mn;
    __syncthreads();
    if (tid == 0) Mmin[row] = fminf(fminf(red[0], red[1]), fminf(red[2], red[3]));
}

// ---- per-launch state init (graph replays: ws/out are NOT re-poisoned) ----
__global__ void init_state(float* __restrict__ ubuf, unsigned* __restrict__ bar,
                           float* __restrict__ out) {
    int idx = blockIdx.x * blockDim.x + threadIdx.x;
    if (idx < 1024) bar[idx] = 0u;
    if (idx < 1024) { ubuf[idx] = 1.0f; ubuf[1024 + idx] = 1.0f; }
    if (idx == 0) out[0] = 0.0f;
}

// ---- register-resident Sinkhorn, custom hierarchical barriers ----
// Block b owns cols [64b,64b+64); thread (rg=tid>>2, ch=tid&3) holds
// K[4][16] = rows 4rg..4rg+3 x cols {64b+ch+4c}. v: LDS ping-pong.
// u: global ping-pong ubuf[2][1024] (speculative update safe at break).
// spart[rowgrp][writer] float4 + errpart live in the consumed M region of d_out.
__global__ __launch_bounds__(1024, 4) void sinkhorn_reg(const float* __restrict__ Mmin,
                                                        float* __restrict__ ubuf,
                                                        float* __restrict__ out,
                                                        unsigned* __restrict__ bar) {
    const int tid = threadIdx.x;
    const int b = blockIdx.x;
    const int rg = tid >> 2;
    const int ch = tid & 3;
    const int r0 = rg << 2;
    const int c0 = b << 6;
    float* Pbuf = out + 1;
    float4* spart4 = (float4*)(out + 4);          // [256 rowgrp][256 writer] float4
    float* errpart = out + 4 + 262144;            // [256]

    __shared__ float v_lds[2][64];
    __shared__ float t_acc[16][68];
    __shared__ float red[16];
    __shared__ float sh_err;

    if (tid < 64) { v_lds[0][tid] = 1.0f; v_lds[1][tid] = 1.0f; }

    // ---- load K = exp(-gamma*(M - Mmin)) into registers ----
    float K[64];
#pragma unroll
    for (int k = 0; k < 4; ++k) {
        const float* mrow = Pbuf + (size_t)(r0 + k) * M_COLS + c0 + ch;
        float mm = Mmin[r0 + k];
#pragma unroll
        for (int c = 0; c < 16; ++c) {
            K[k * 16 + c] = __expf(-GAMMA_ * (mrow[4 * c] - mm));
        }
    }
    gbar(bar, b, tid, 1u);   // M fully consumed; scratch region now writable

    int cur = 0, vsel = 0;
    unsigned ep = 2u;
    int it = 0;
    for (;; ++it, ep += 2u) {
        // ---- pass 1: this block's 64-col partial of s, all 1024 rows ----
        {
            float vv[16];
#pragma unroll
            for (int c = 0; c < 16; ++c) vv[c] = v_lds[cur][ch + 4 * c];
            float rs[4];
#pragma unroll
            for (int k = 0; k < 4; ++k) {
                float p = 0.f;
#pragma unroll
                for (int c = 0; c < 16; ++c) p = fmaf(K[k * 16 + c], vv[c], p);
                rs[k] = p;
            }
#pragma unroll
            for (int k = 0; k < 4; ++k) {
                rs[k] += __shfl_xor(rs[k], 1);
                rs[k] += __shfl_xor(rs[k], 2);
            }
            if (ch == 0) spart4[rg * 256 + b] = make_float4(rs[0], rs[1], rs[2], rs[3]);
        }
        gbar(bar, b, tid, ep);   // barrier A: spart + prev errpart visible
        // ---- window 1 (overlapped): wave0 = err check, waves1..4 = u update ----
        float* uOld = ubuf + (((it & 1) ^ 1) << 10);
        float* uNew = ubuf + ((it & 1) << 10);
        {
            const int w = tid >> 6, l = tid & 63;
            if (w == 0) {
                float e = 0.f;
                if (it > 0) e = errpart[l] + errpart[l + 64] + errpart[l + 128] + errpart[l + 192];
                e = waveRedSum(e);
                if (l == 0) sh_err = (it > 0) ? e : 1e30f;
            } else if (w <= 4) {
                int r = (b << 2) + (w - 1);
                const float* sp = out + 4 + ((size_t)b << 10) + (w - 1);
                float s = sp[4 * l] + sp[4 * (l + 64)] + sp[4 * (l + 128)] + sp[4 * (l + 192)];
                s = waveRedSum(s);
                if (l == 0) {
                    float uo = uOld[r];
                    uNew[r] = uo * RVAL / fmaxf(uo * s, TINY_);   // speculative at break iter
                }
            }
        }
        __syncthreads();
        float err = sh_err;
        if (err <= EPS_) { vsel = cur ^ 1; break; }   // converged: keep V[t-2], U[t-1]
        if (it == 1000) { vsel = cur; break; }        // exhausted: keep V[999], U[999]
        gbar(bar, b, tid, ep + 1u);   // barrier B: all uNew visible
        // ---- pass 2: t = K^T u for own 64 cols; v update; err partial ----
        {
            float4 u4 = *(const float4*)(uNew + r0);
            float uu[4] = {u4.x, u4.y, u4.z, u4.w};
            float t16[16];
#pragma unroll
            for (int c = 0; c < 16; ++c) {
                float t = 0.f;
#pragma unroll
                for (int k = 0; k < 4; ++k) t = fmaf(K[k * 16 + c], uu[k], t);
                t16[c] = t;
            }
#pragma unroll
            for (int c = 0; c < 16; ++c) {
                t16[c] += __shfl_xor(t16[c], 4);
                t16[c] += __shfl_xor(t16[c], 8);
                t16[c] += __shfl_xor(t16[c], 16);
                t16[c] += __shfl_xor(t16[c], 32);
            }
            const int w = tid >> 6, l = tid & 63;
            if (l < 4) {
#pragma unroll
                for (int c = 0; c < 16; ++c) t_acc[w][l + 4 * c] = t16[c];
            }
        }
        __syncthreads();
        if (tid < 64) {
            float t = 0.f;
#pragma unroll
            for (int w2 = 0; w2 < 16; ++w2) t += t_acc[w2][tid];
            float vc = v_lds[cur][tid];
            float beta = vc * t;
            float e = fabsf(beta - CVAL);
            v_lds[cur ^ 1][tid] = vc * CVAL / fmaxf(beta, TINY_);
            e = waveRedSum(e);
            if (tid == 0) errpart[b] = e;
        }
        __syncthreads();
        cur ^= 1;
    }

    gbar(bar, b, tid, ep + 1u);   // all errcheck/spart reads done before P overwrites scratch

    // ---- epilogue: P = u K v (regs); loss = sum P*(Mmin - ln(K)/gamma) ----
    float* uEpi = ubuf + (((it & 1) ^ 1) << 10);   // U[t-1] (or U[999] on exhaustion)
    float vv[16];
#pragma unroll
    for (int c = 0; c < 16; ++c) vv[c] = v_lds[vsel][ch + 4 * c];
    float4 u4 = *(const float4*)(uEpi + r0);
    float uu[4] = {u4.x, u4.y, u4.z, u4.w};
    float4 mm4 = *(const float4*)(Mmin + r0);
    float mm[4] = {mm4.x, mm4.y, mm4.z, mm4.w};
    float lsum = 0.f;
#pragma unroll
    for (int k = 0; k < 4; ++k) {
        float* prow = Pbuf + (size_t)(r0 + k) * M_COLS + c0 + ch;
#pragma unroll
        for (int c = 0; c < 16; ++c) {
            float kv = K[k * 16 + c];
            float p = 0.f;
            if (kv > 0.f) {
                p = uu[k] * kv * vv[c];
                float m = mm[k] - __logf(kv) * INV_GAMMA;
                lsum = fmaf(p, m, lsum);
            }
            prow[4 * c] = p;
        }
    }
    lsum = waveRedSum(lsum);
    if ((tid & 63) == 0) red[tid >> 6] = lsum;
    __syncthreads();
    if (tid == 0) {
        float s = 0.f;
#pragma unroll
        for (int i = 0; i < 16; ++i) s += red[i];
        atomicAdd(out, s);
    }
}

extern "C" void kernel_launch(void* const* d_in, const int* in_sizes, int n_in,
                              void* d_out, int out_size, void* d_ws, size_t ws_size,
                              hipStream_t stream) {
    const float* x = (const float*)d_in[0];
    const float* y = (const float*)d_in[1];
    float* out = (float*)d_out;
    float* P = out + 1;
    float* ws = (float*)d_ws;
    float* sx   = ws;                       // 1024
    float* sy   = ws + 1024;                // 16384
    float* Mmin = ws + 17408;               // 1024
    float* ubuf = ws + 18432;               // 2 x 1024
    unsigned* bar = (unsigned*)(ws + 20480); // 1024 uints

    row_sqnorm<<<N_ROWS, 128, 0, stream>>>(x, sx);
    row_sqnorm<<<M_COLS, 128, 0, stream>>>(y, sy);
    init_state<<<4, 256, 0, stream>>>(ubuf, bar, out);
    gemm_dist<<<dim3(128, 8), 256, 0, stream>>>(x, y, sx, sy, P);
    row_min<<<N_ROWS, 256, 0, stream>>>(P, Mmin);
    {
        const float* Mminc = Mmin;
        void* args[] = {(void*)&Mminc, (void*)&ubuf, (void*)&out, (void*)&bar};
        hipLaunchCooperativeKernel((const void*)sinkhorn_reg, dim3(256), dim3(1024), args, 0, stream);
    }
}

// Round 4
// 375.027 us; speedup vs baseline: 2.2596x; 2.2596x over previous
//
#include <hip/hip_runtime.h>

#define N_ROWS 1024
#define M_COLS 16384
#define DIM 512

constexpr float GAMMA_ = 0.1f;
constexpr float INV_GAMMA = 10.0f;
constexpr float EPS_ = 0.005f;
constexpr float TINY_ = 1e-30f;
constexpr float RVAL = 1.0f / 1024.0f;
constexpr float CVAL = 1.0f / 16384.0f;

__device__ __forceinline__ float waveRedSum(float v) {
#pragma unroll
    for (int o = 32; o > 0; o >>= 1) v += __shfl_down(v, o);
    return v;
}
__device__ __forceinline__ float waveRedMin(float v) {
#pragma unroll
    for (int o = 32; o > 0; o >>= 1) v = fminf(v, __shfl_down(v, o));
    return v;
}

// ---- L2-bypassing (coherent-point) accesses: relaxed system-scope atomics ----
// On gfx950 these emit global_load/store with sc0 sc1 (bypass L1+L2, served at
// L3/memory side) -> cross-XCD visible without any wbl2/inv fences.
__device__ __forceinline__ unsigned sysloadu(const unsigned* p) {
    return __hip_atomic_load(p, __ATOMIC_RELAXED, __HIP_MEMORY_SCOPE_SYSTEM);
}
__device__ __forceinline__ void sysstoreu(unsigned* p, unsigned v) {
    __hip_atomic_store(p, v, __ATOMIC_RELAXED, __HIP_MEMORY_SCOPE_SYSTEM);
}
__device__ __forceinline__ float sysloadf(const float* p) {
    return __hip_atomic_load(p, __ATOMIC_RELAXED, __HIP_MEMORY_SCOPE_SYSTEM);
}
__device__ __forceinline__ void sysstoref(float* p, float v) {
    __hip_atomic_store(p, v, __ATOMIC_RELAXED, __HIP_MEMORY_SCOPE_SYSTEM);
}

// ---- fence-free symmetric barrier ----
// arrival[256] contiguous; bcast on a separate line. Data published with
// sys-stores BEFORE the entry __syncthreads (whose vmcnt(0) drain acks them
// at L3); arrival flag then proves this block's data is globally visible.
// Block 0 sweeps all arrivals (4 waves) and publishes one broadcast epoch.
__device__ __forceinline__ void gbarx(unsigned* __restrict__ arr, unsigned* __restrict__ bcast,
                                      int b, int tid, unsigned e) {
    __syncthreads();                       // drains vmcnt: all waves' sys-stores acked at L3
    if (tid == 0) sysstoreu(&arr[b], e);   // publish arrival
    if (b == 0) {
        if (tid < 256) {
            while (sysloadu(&arr[tid]) < e) __builtin_amdgcn_s_sleep(1);
        }
        __syncthreads();                   // all 256 sweep lanes satisfied
        if (tid == 0) sysstoreu(bcast, e);
    } else {
        if (tid == 0) {
            while (sysloadu(bcast) < e) __builtin_amdgcn_s_sleep(1);
        }
    }
    __syncthreads();
}

// ---- sq norms: one block (128 thr) per row ----
__global__ void row_sqnorm(const float* __restrict__ X, float* __restrict__ out) {
    int row = blockIdx.x;
    const float* xr = X + (size_t)row * DIM;
    int tid = threadIdx.x;
    float acc = 0.f;
    for (int k = tid; k < DIM; k += 128) { float v = xr[k]; acc = fmaf(v, v, acc); }
    acc = waveRedSum(acc);
    __shared__ float red[2];
    if ((tid & 63) == 0) red[tid >> 6] = acc;
    __syncthreads();
    if (tid == 0) out[row] = red[0] + red[1];
}

// ---- M = sx + sy - 2*X@Y^T  (f32, 128x128 tile, 8x8/thread) ----
__global__ __launch_bounds__(256) void gemm_dist(const float* __restrict__ X, const float* __restrict__ Y,
                                                 const float* __restrict__ sx, const float* __restrict__ sy,
                                                 float* __restrict__ Mout) {
    alignas(16) __shared__ float As[16][132];
    alignas(16) __shared__ float Bs[16][132];
    const int tid = threadIdx.x;
    const int tx = tid & 15, ty = tid >> 4;
    const int row0 = blockIdx.y * 128, col0 = blockIdx.x * 128;
    float acc[8][8] = {};
    for (int k0 = 0; k0 < DIM; k0 += 16) {
#pragma unroll
        for (int p = 0; p < 2; ++p) {
            int idx = tid + (p << 8);
            int r = idx >> 2;
            int kq = (idx & 3) << 2;
            float4 va = *(const float4*)(X + (size_t)(row0 + r) * DIM + k0 + kq);
            As[kq + 0][r] = va.x; As[kq + 1][r] = va.y; As[kq + 2][r] = va.z; As[kq + 3][r] = va.w;
            float4 vb = *(const float4*)(Y + (size_t)(col0 + r) * DIM + k0 + kq);
            Bs[kq + 0][r] = vb.x; Bs[kq + 1][r] = vb.y; Bs[kq + 2][r] = vb.z; Bs[kq + 3][r] = vb.w;
        }
        __syncthreads();
#pragma unroll
        for (int kk = 0; kk < 16; ++kk) {
            float a[8], bq[8];
            *(float4*)&a[0] = *(const float4*)&As[kk][ty * 8];
            *(float4*)&a[4] = *(const float4*)&As[kk][ty * 8 + 4];
            *(float4*)&bq[0] = *(const float4*)&Bs[kk][tx * 8];
            *(float4*)&bq[4] = *(const float4*)&Bs[kk][tx * 8 + 4];
#pragma unroll
            for (int i = 0; i < 8; ++i)
#pragma unroll
                for (int j = 0; j < 8; ++j)
                    acc[i][j] = fmaf(a[i], bq[j], acc[i][j]);
        }
        __syncthreads();
    }
#pragma unroll
    for (int i = 0; i < 8; ++i) {
        int gr = row0 + ty * 8 + i;
        float sxi = sx[gr];
        float* orow = Mout + (size_t)gr * M_COLS + col0 + tx * 8;
#pragma unroll
        for (int j = 0; j < 8; ++j) {
            orow[j] = sxi + sy[col0 + tx * 8 + j] - 2.0f * acc[i][j];
        }
    }
}

// ---- row min of M ----
__global__ void row_min(const float* __restrict__ Mb, float* __restrict__ Mmin) {
    int row = blockIdx.x;
    const float* mr = Mb + (size_t)row * M_COLS;
    int tid = threadIdx.x;
    float mn = INFINITY;
    for (int j = tid; j < M_COLS; j += 256) mn = fminf(mn, mr[j]);
    mn = waveRedMin(mn);
    __shared__ float red[4];
    if ((tid & 63) == 0) red[tid >> 6] = mn;
    __syncthreads();
    if (tid == 0) Mmin[row] = fminf(fminf(red[0], red[1]), fminf(red[2], red[3]));
}

// ---- per-launch state init (graph replays do NOT re-poison ws/out) ----
__global__ void init_state(float* __restrict__ ubuf, unsigned* __restrict__ bar,
                           float* __restrict__ out) {
    int idx = blockIdx.x * blockDim.x + threadIdx.x;
    if (idx < 512) bar[idx] = 0u;
    if (idx < 1024) { ubuf[idx] = 1.0f; ubuf[1024 + idx] = 1.0f; }
    if (idx == 0) out[0] = 0.0f;
}

// ---- register-resident Sinkhorn, fence-free flag barriers ----
// Block b owns cols [64b,64b+64); thread (rg=tid>>2, ch=tid&3) holds
// K[4][16] = rows 4rg..4rg+3 x cols {64b+ch+4c}. v: LDS ping-pong.
// u: global ping-pong ubuf[2][1024] via sys-atomics. spart[rg][writer][k]
// and errpart live in the consumed M region of d_out; all cross-block
// traffic goes through sc0/sc1 (L3-coherent) accesses -> no fences.
__global__ __launch_bounds__(1024, 4) void sinkhorn_reg(const float* __restrict__ Mmin,
                                                        float* __restrict__ ubuf,
                                                        float* __restrict__ out,
                                                        unsigned* __restrict__ bar) {
    const int tid = threadIdx.x;
    const int b = blockIdx.x;
    const int rg = tid >> 2;
    const int ch = tid & 3;
    const int r0 = rg << 2;
    const int c0 = b << 6;
    float* Pbuf = out + 1;
    float* spart = out + 4;               // [256 rg][256 writer][4 k] floats (1 MB)
    float* errpart = out + 4 + 262144;    // [256]
    unsigned* arr = bar;                  // [256]
    unsigned* bcast = bar + 288;          // separate cache line

    __shared__ float v_lds[2][64];
    __shared__ float u_lds[1024];
    __shared__ float t_acc[16][68];
    __shared__ float red[16];
    __shared__ float sh_err;

    if (tid < 64) { v_lds[0][tid] = 1.0f; v_lds[1][tid] = 1.0f; }

    // ---- load K = exp(-gamma*(M - Mmin)) into registers (normal cached loads;
    // M was written by a prior kernel -> visible via stream ordering) ----
    float K[64];
#pragma unroll
    for (int k = 0; k < 4; ++k) {
        const float* mrow = Pbuf + (size_t)(r0 + k) * M_COLS + c0 + ch;
        float mm = Mmin[r0 + k];
#pragma unroll
        for (int c = 0; c < 16; ++c) {
            K[k * 16 + c] = __expf(-GAMMA_ * (mrow[4 * c] - mm));
        }
    }
    gbarx(arr, bcast, b, tid, 1u);   // M fully consumed; scratch region writable

    int cur = 0, vsel = 0, brk = 0;
    unsigned ep = 2u;
    int it = 0;
    for (;; ++it, ep += 2u) {
        // ---- pass 1: this block's 64-col partial of s, all 1024 rows ----
        {
            float vv[16];
#pragma unroll
            for (int c = 0; c < 16; ++c) vv[c] = v_lds[cur][ch + 4 * c];
            float rs[4];
#pragma unroll
            for (int k = 0; k < 4; ++k) {
                float p = 0.f;
#pragma unroll
                for (int c = 0; c < 16; ++c) p = fmaf(K[k * 16 + c], vv[c], p);
                rs[k] = p;
            }
#pragma unroll
            for (int k = 0; k < 4; ++k) {
                rs[k] += __shfl_xor(rs[k], 1);
                rs[k] += __shfl_xor(rs[k], 2);
            }
            // every lane of the quad holds all rs[0..3]; lane ch stores element ch
            sysstoref(&spart[(size_t)(rg * 256 + b) * 4 + ch], rs[ch]);
        }
        gbarx(arr, bcast, b, tid, ep);   // barrier A: spart + prev errpart visible
        // ---- window 1: wave0 = err check (err of prev iter), waves1..4 = u update ----
        float* uOld = ubuf + (((it & 1) ^ 1) << 10);
        float* uNew = ubuf + ((it & 1) << 10);
        {
            const int w = tid >> 6, l = tid & 63;
            if (w == 0) {
                float e = 0.f;
                if (it > 0)
                    e = sysloadf(&errpart[l]) + sysloadf(&errpart[l + 64]) +
                        sysloadf(&errpart[l + 128]) + sysloadf(&errpart[l + 192]);
                e = waveRedSum(e);
                if (l == 0) sh_err = (it > 0) ? e : 1e30f;
            } else if (w <= 4) {
                const int k = w - 1;
                const float* sp = spart + ((size_t)b << 10) + k;
                float s = sysloadf(&sp[4 * l]) + sysloadf(&sp[4 * (l + 64)]) +
                          sysloadf(&sp[4 * (l + 128)]) + sysloadf(&sp[4 * (l + 192)]);
                s = waveRedSum(s);
                if (l == 0) {
                    int r = (b << 2) + k;
                    float uo = sysloadf(&uOld[r]);
                    sysstoref(&uNew[r], uo * RVAL / fmaxf(uo * s, TINY_));  // speculative at break
                }
            }
        }
        __syncthreads();
        float err = sh_err;
        brk = (err <= EPS_) ? 1 : ((it == 1000) ? 2 : 0);
        gbarx(arr, bcast, b, tid, ep + 1u);  // barrier B: u visible / epilogue-safety
        if (brk) { vsel = (brk == 1) ? (cur ^ 1) : cur; break; }
        // ---- u -> LDS broadcast ----
        if (tid < 256) {
#pragma unroll
            for (int k = 0; k < 4; ++k) u_lds[tid * 4 + k] = sysloadf(&uNew[tid * 4 + k]);
        }
        __syncthreads();
        // ---- pass 2: t = K^T u for own 64 cols; v update; err partial ----
        {
            float uu[4] = {u_lds[r0], u_lds[r0 + 1], u_lds[r0 + 2], u_lds[r0 + 3]};
            float t16[16];
#pragma unroll
            for (int c = 0; c < 16; ++c) {
                float t = 0.f;
#pragma unroll
                for (int k = 0; k < 4; ++k) t = fmaf(K[k * 16 + c], uu[k], t);
                t16[c] = t;
            }
#pragma unroll
            for (int c = 0; c < 16; ++c) {
                t16[c] += __shfl_xor(t16[c], 4);
                t16[c] += __shfl_xor(t16[c], 8);
                t16[c] += __shfl_xor(t16[c], 16);
                t16[c] += __shfl_xor(t16[c], 32);
            }
            const int w = tid >> 6, l = tid & 63;
            if (l < 4) {
#pragma unroll
                for (int c = 0; c < 16; ++c) t_acc[w][l + 4 * c] = t16[c];
            }
        }
        __syncthreads();
        if (tid < 64) {
            float t = 0.f;
#pragma unroll
            for (int w2 = 0; w2 < 16; ++w2) t += t_acc[w2][tid];
            float vc = v_lds[cur][tid];
            float beta = vc * t;
            float e = fabsf(beta - CVAL);
            v_lds[cur ^ 1][tid] = vc * CVAL / fmaxf(beta, TINY_);
            e = waveRedSum(e);
            if (tid == 0) sysstoref(&errpart[b], e);
        }
        __syncthreads();
        cur ^= 1;
    }

    // ---- epilogue: P = u K v (regs); loss = sum P*(Mmin - ln(K)/gamma) ----
    const float* uEpi = ubuf + (((it & 1) ^ 1) << 10);
    float vv[16];
#pragma unroll
    for (int c = 0; c < 16; ++c) vv[c] = v_lds[vsel][ch + 4 * c];
    float uu[4];
#pragma unroll
    for (int k = 0; k < 4; ++k) uu[k] = sysloadf(&uEpi[r0 + k]);
    float4 mm4 = *(const float4*)(Mmin + r0);
    float mm[4] = {mm4.x, mm4.y, mm4.z, mm4.w};
    float lsum = 0.f;
#pragma unroll
    for (int k = 0; k < 4; ++k) {
        float* prow = Pbuf + (size_t)(r0 + k) * M_COLS + c0 + ch;
#pragma unroll
        for (int c = 0; c < 16; ++c) {
            float kv = K[k * 16 + c];
            float p = 0.f;
            if (kv > 0.f) {
                p = uu[k] * kv * vv[c];
                float m = mm[k] - __logf(kv) * INV_GAMMA;
                lsum = fmaf(p, m, lsum);
            }
            prow[4 * c] = p;
        }
    }
    lsum = waveRedSum(lsum);
    if ((tid & 63) == 0) red[tid >> 6] = lsum;
    __syncthreads();
    if (tid == 0) {
        float s = 0.f;
#pragma unroll
        for (int i = 0; i < 16; ++i) s += red[i];
        atomicAdd(out, s);
    }
}

extern "C" void kernel_launch(void* const* d_in, const int* in_sizes, int n_in,
                              void* d_out, int out_size, void* d_ws, size_t ws_size,
                              hipStream_t stream) {
    const float* x = (const float*)d_in[0];
    const float* y = (const float*)d_in[1];
    float* out = (float*)d_out;
    float* P = out + 1;
    float* ws = (float*)d_ws;
    float* sx   = ws;                        // 1024
    float* sy   = ws + 1024;                 // 16384
    float* Mmin = ws + 17408;                // 1024
    float* ubuf = ws + 18432;                // 2 x 1024
    unsigned* bar = (unsigned*)(ws + 20480); // 512 uints

    row_sqnorm<<<N_ROWS, 128, 0, stream>>>(x, sx);
    row_sqnorm<<<M_COLS, 128, 0, stream>>>(y, sy);
    init_state<<<4, 256, 0, stream>>>(ubuf, bar, out);
    gemm_dist<<<dim3(128, 8), 256, 0, stream>>>(x, y, sx, sy, P);
    row_min<<<N_ROWS, 256, 0, stream>>>(P, Mmin);
    {
        const float* Mminc = Mmin;
        void* args[] = {(void*)&Mminc, (void*)&ubuf, (void*)&out, (void*)&bar};
        hipLaunchCooperativeKernel((const void*)sinkhorn_reg, dim3(256), dim3(1024), args, 0, stream);
    }
}

// Round 5
// 258.242 us; speedup vs baseline: 3.2814x; 1.4522x over previous
//
#include <hip/hip_runtime.h>

#define N_ROWS 1024
#define M_COLS 16384
#define DIM 512

constexpr float GAMMA_ = 0.1f;
constexpr float INV_GAMMA = 10.0f;
constexpr float EPS_ = 0.005f;
constexpr float TINY_ = 1e-30f;
constexpr float RVAL = 1.0f / 1024.0f;
constexpr float CVAL = 1.0f / 16384.0f;

typedef __attribute__((ext_vector_type(8))) short bf16x8;
typedef __attribute__((ext_vector_type(4))) float f32x4;

__device__ __forceinline__ float waveRedSum(float v) {
#pragma unroll
    for (int o = 32; o > 0; o >>= 1) v += __shfl_down(v, o);
    return v;
}
__device__ __forceinline__ float waveRedMin(float v) {
#pragma unroll
    for (int o = 32; o > 0; o >>= 1) v = fminf(v, __shfl_down(v, o));
    return v;
}

// ---- L2-bypassing (coherent-point) accesses: relaxed system-scope atomics ----
__device__ __forceinline__ unsigned sysloadu(const unsigned* p) {
    return __hip_atomic_load(p, __ATOMIC_RELAXED, __HIP_MEMORY_SCOPE_SYSTEM);
}
__device__ __forceinline__ void sysstoreu(unsigned* p, unsigned v) {
    __hip_atomic_store(p, v, __ATOMIC_RELAXED, __HIP_MEMORY_SCOPE_SYSTEM);
}
__device__ __forceinline__ float sysloadf(const float* p) {
    return __hip_atomic_load(p, __ATOMIC_RELAXED, __HIP_MEMORY_SCOPE_SYSTEM);
}
__device__ __forceinline__ void sysstoref(float* p, float v) {
    __hip_atomic_store(p, v, __ATOMIC_RELAXED, __HIP_MEMORY_SCOPE_SYSTEM);
}

// ---- fence-free symmetric barrier (see R4: ~1 us) ----
__device__ __forceinline__ void gbarx(unsigned* __restrict__ arr, unsigned* __restrict__ bcast,
                                      int b, int tid, unsigned e) {
    __syncthreads();
    if (tid == 0) sysstoreu(&arr[b], e);
    if (b == 0) {
        if (tid < 256) {
            while (sysloadu(&arr[tid]) < e) __builtin_amdgcn_s_sleep(1);
        }
        __syncthreads();
        if (tid == 0) sysstoreu(bcast, e);
    } else {
        if (tid == 0) {
            while (sysloadu(bcast) < e) __builtin_amdgcn_s_sleep(1);
        }
    }
    __syncthreads();
}

// ---- sq norms: one block (128 thr) per row ----
__global__ void row_sqnorm(const float* __restrict__ X, float* __restrict__ out) {
    int row = blockIdx.x;
    const float* xr = X + (size_t)row * DIM;
    int tid = threadIdx.x;
    float acc = 0.f;
    for (int k = tid; k < DIM; k += 128) { float v = xr[k]; acc = fmaf(v, v, acc); }
    acc = waveRedSum(acc);
    __shared__ float red[2];
    if ((tid & 63) == 0) red[tid >> 6] = acc;
    __syncthreads();
    if (tid == 0) out[row] = red[0] + red[1];
}

// ---- bf16 split helpers ----
__device__ __forceinline__ unsigned bf16b(float f) {
    unsigned u = __float_as_uint(f);
    return (u + 0x7FFFu + ((u >> 16) & 1u)) >> 16;
}

// ---- M = sx + sy - 2*X@Y^T via split-bf16 MFMA (3 passes: hh + hl + lh) ----
// 128x128 tile, BK=64, 4 waves (2x2), mfma_f32_16x16x32_bf16.
// LDS: A/B tiles as bf16 [128][64] hi+lo with XOR swizzle off^=((r&7)<<4).
__global__ __launch_bounds__(256, 2) void gemm_dist_mfma(const float* __restrict__ X, const float* __restrict__ Y,
                                                         const float* __restrict__ sx, const float* __restrict__ sy,
                                                         float* __restrict__ Mout) {
    __shared__ __align__(16) char lds[65536];
    char* Ahi = lds;
    char* Alo = lds + 16384;
    char* Bhi = lds + 32768;
    char* Blo = lds + 49152;
    const int tid = threadIdx.x;
    const int lane = tid & 63;
    const int w = tid >> 6;
    const int wm = w >> 1, wn = w & 1;
    // XCD-contiguous swizzle (bijective: 1024 wgs / 8 XCDs = 128 each);
    // logical = ct*8+rt so one XCD sees 16 col-panels (4MB y in L2) x all 8 row-tiles
    const int bid = blockIdx.x;
    const int logical = (bid & 7) * 128 + (bid >> 3);
    const int ct = logical >> 3, rt = logical & 7;
    const int row0 = rt << 7, col0 = ct << 7;

    const int srow = tid >> 2;      // staging: 4 threads per row
    const int squar = tid & 3;      // 16-f32 quarter within the 64-k row

    f32x4 acc[4][4] = {};

    for (int k0 = 0; k0 < DIM; k0 += 64) {
        __syncthreads();
        // ---- stage: f32 -> bf16 hi/lo -> LDS (swizzled) ----
#pragma unroll
        for (int rr = 0; rr < 2; ++rr) {
            const int r = rr * 64 + srow;
            const int swz = (r & 7) << 4;
#pragma unroll
            for (int q = 0; q < 4; ++q) {
                const int kk = squar * 16 + q * 4;
                const int off = (r * 128 + kk * 2) ^ swz;
                {
                    float4 va = *(const float4*)(X + (size_t)(row0 + r) * DIM + k0 + kk);
                    unsigned h0 = bf16b(va.x), h1 = bf16b(va.y), h2 = bf16b(va.z), h3 = bf16b(va.w);
                    float l0f = va.x - __uint_as_float(h0 << 16);
                    float l1f = va.y - __uint_as_float(h1 << 16);
                    float l2f = va.z - __uint_as_float(h2 << 16);
                    float l3f = va.w - __uint_as_float(h3 << 16);
                    *(uint2*)(Ahi + off) = make_uint2(h0 | (h1 << 16), h2 | (h3 << 16));
                    *(uint2*)(Alo + off) = make_uint2(bf16b(l0f) | (bf16b(l1f) << 16),
                                                      bf16b(l2f) | (bf16b(l3f) << 16));
                }
                {
                    float4 vb = *(const float4*)(Y + (size_t)(col0 + r) * DIM + k0 + kk);
                    unsigned h0 = bf16b(vb.x), h1 = bf16b(vb.y), h2 = bf16b(vb.z), h3 = bf16b(vb.w);
                    float l0f = vb.x - __uint_as_float(h0 << 16);
                    float l1f = vb.y - __uint_as_float(h1 << 16);
                    float l2f = vb.z - __uint_as_float(h2 << 16);
                    float l3f = vb.w - __uint_as_float(h3 << 16);
                    *(uint2*)(Bhi + off) = make_uint2(h0 | (h1 << 16), h2 | (h3 << 16));
                    *(uint2*)(Blo + off) = make_uint2(bf16b(l0f) | (bf16b(l1f) << 16),
                                                      bf16b(l2f) | (bf16b(l3f) << 16));
                }
            }
        }
        __syncthreads();
        // ---- compute: 2 k-slices x 4x4 frags x 3 mfma ----
#pragma unroll
        for (int ks = 0; ks < 2; ++ks) {
            const int kb = (ks * 32 + (lane >> 4) * 8) * 2;
            bf16x8 ah[4], al[4], bh[4], bl[4];
#pragma unroll
            for (int i = 0; i < 4; ++i) {
                const int r = wm * 64 + i * 16 + (lane & 15);
                const int offa = (r * 128 + kb) ^ ((r & 7) << 4);
                ah[i] = *(const bf16x8*)(Ahi + offa);
                al[i] = *(const bf16x8*)(Alo + offa);
                const int c = wn * 64 + i * 16 + (lane & 15);
                const int offb = (c * 128 + kb) ^ ((c & 7) << 4);
                bh[i] = *(const bf16x8*)(Bhi + offb);
                bl[i] = *(const bf16x8*)(Blo + offb);
            }
#pragma unroll
            for (int i = 0; i < 4; ++i)
#pragma unroll
                for (int j = 0; j < 4; ++j) {
                    acc[i][j] = __builtin_amdgcn_mfma_f32_16x16x32_bf16(ah[i], bh[j], acc[i][j], 0, 0, 0);
                    acc[i][j] = __builtin_amdgcn_mfma_f32_16x16x32_bf16(ah[i], bl[j], acc[i][j], 0, 0, 0);
                    acc[i][j] = __builtin_amdgcn_mfma_f32_16x16x32_bf16(al[i], bh[j], acc[i][j], 0, 0, 0);
                }
        }
    }
    // ---- epilogue: M = sx + sy - 2*acc  (C/D: col=lane&15, row=(lane>>4)*4+q) ----
    const int lrow = lane >> 4;
    const int lcol = lane & 15;
#pragma unroll
    for (int i = 0; i < 4; ++i) {
        const int gr0 = row0 + wm * 64 + i * 16 + lrow * 4;
        const float sx0 = sx[gr0], sx1 = sx[gr0 + 1], sx2 = sx[gr0 + 2], sx3 = sx[gr0 + 3];
#pragma unroll
        for (int j = 0; j < 4; ++j) {
            const int gc = col0 + wn * 64 + j * 16 + lcol;
            const float syv = sy[gc];
            float* op = Mout + (size_t)gr0 * M_COLS + gc;
            op[0]                     = sx0 + syv - 2.0f * acc[i][j][0];
            op[(size_t)1 * M_COLS]    = sx1 + syv - 2.0f * acc[i][j][1];
            op[(size_t)2 * M_COLS]    = sx2 + syv - 2.0f * acc[i][j][2];
            op[(size_t)3 * M_COLS]    = sx3 + syv - 2.0f * acc[i][j][3];
        }
    }
}

// ---- row min of M ----
__global__ void row_min(const float* __restrict__ Mb, float* __restrict__ Mmin) {
    int row = blockIdx.x;
    const float* mr = Mb + (size_t)row * M_COLS;
    int tid = threadIdx.x;
    float mn = INFINITY;
    for (int j = tid; j < M_COLS; j += 256) mn = fminf(mn, mr[j]);
    mn = waveRedMin(mn);
    __shared__ float red[4];
    if ((tid & 63) == 0) red[tid >> 6] = mn;
    __syncthreads();
    if (tid == 0) Mmin[row] = fminf(fminf(red[0], red[1]), fminf(red[2], red[3]));
}

// ---- per-launch state init (graph replays do NOT re-poison ws/out) ----
__global__ void init_state(float* __restrict__ ubuf, unsigned* __restrict__ bar,
                           float* __restrict__ out) {
    int idx = blockIdx.x * blockDim.x + threadIdx.x;
    if (idx < 512) bar[idx] = 0u;
    if (idx < 1024) { ubuf[idx] = 1.0f; ubuf[1024 + idx] = 1.0f; }
    if (idx == 0) out[0] = 0.0f;
}

// ---- register-resident Sinkhorn, fence-free flag barriers (R4, unchanged) ----
__global__ __launch_bounds__(1024, 4) void sinkhorn_reg(const float* __restrict__ Mmin,
                                                        float* __restrict__ ubuf,
                                                        float* __restrict__ out,
                                                        unsigned* __restrict__ bar) {
    const int tid = threadIdx.x;
    const int b = blockIdx.x;
    const int rg = tid >> 2;
    const int ch = tid & 3;
    const int r0 = rg << 2;
    const int c0 = b << 6;
    float* Pbuf = out + 1;
    float* spart = out + 4;               // [256 rg][256 writer][4 k] floats (1 MB)
    float* errpart = out + 4 + 262144;    // [256]
    unsigned* arr = bar;                  // [256]
    unsigned* bcast = bar + 288;          // separate cache line

    __shared__ float v_lds[2][64];
    __shared__ float u_lds[1024];
    __shared__ float t_acc[16][68];
    __shared__ float red[16];
    __shared__ float sh_err;

    if (tid < 64) { v_lds[0][tid] = 1.0f; v_lds[1][tid] = 1.0f; }

    float K[64];
#pragma unroll
    for (int k = 0; k < 4; ++k) {
        const float* mrow = Pbuf + (size_t)(r0 + k) * M_COLS + c0 + ch;
        float mm = Mmin[r0 + k];
#pragma unroll
        for (int c = 0; c < 16; ++c) {
            K[k * 16 + c] = __expf(-GAMMA_ * (mrow[4 * c] - mm));
        }
    }
    gbarx(arr, bcast, b, tid, 1u);   // M fully consumed; scratch region writable

    int cur = 0, vsel = 0, brk = 0;
    unsigned ep = 2u;
    int it = 0;
    for (;; ++it, ep += 2u) {
        {
            float vv[16];
#pragma unroll
            for (int c = 0; c < 16; ++c) vv[c] = v_lds[cur][ch + 4 * c];
            float rs[4];
#pragma unroll
            for (int k = 0; k < 4; ++k) {
                float p = 0.f;
#pragma unroll
                for (int c = 0; c < 16; ++c) p = fmaf(K[k * 16 + c], vv[c], p);
                rs[k] = p;
            }
#pragma unroll
            for (int k = 0; k < 4; ++k) {
                rs[k] += __shfl_xor(rs[k], 1);
                rs[k] += __shfl_xor(rs[k], 2);
            }
            sysstoref(&spart[(size_t)(rg * 256 + b) * 4 + ch], rs[ch]);
        }
        gbarx(arr, bcast, b, tid, ep);   // barrier A
        float* uOld = ubuf + (((it & 1) ^ 1) << 10);
        float* uNew = ubuf + ((it & 1) << 10);
        {
            const int w = tid >> 6, l = tid & 63;
            if (w == 0) {
                float e = 0.f;
                if (it > 0)
                    e = sysloadf(&errpart[l]) + sysloadf(&errpart[l + 64]) +
                        sysloadf(&errpart[l + 128]) + sysloadf(&errpart[l + 192]);
                e = waveRedSum(e);
                if (l == 0) sh_err = (it > 0) ? e : 1e30f;
            } else if (w <= 4) {
                const int k = w - 1;
                const float* sp = spart + ((size_t)b << 10) + k;
                float s = sysloadf(&sp[4 * l]) + sysloadf(&sp[4 * (l + 64)]) +
                          sysloadf(&sp[4 * (l + 128)]) + sysloadf(&sp[4 * (l + 192)]);
                s = waveRedSum(s);
                if (l == 0) {
                    int r = (b << 2) + k;
                    float uo = sysloadf(&uOld[r]);
                    sysstoref(&uNew[r], uo * RVAL / fmaxf(uo * s, TINY_));
                }
            }
        }
        __syncthreads();
        float err = sh_err;
        brk = (err <= EPS_) ? 1 : ((it == 1000) ? 2 : 0);
        gbarx(arr, bcast, b, tid, ep + 1u);  // barrier B
        if (brk) { vsel = (brk == 1) ? (cur ^ 1) : cur; break; }
        if (tid < 256) {
#pragma unroll
            for (int k = 0; k < 4; ++k) u_lds[tid * 4 + k] = sysloadf(&uNew[tid * 4 + k]);
        }
        __syncthreads();
        {
            float uu[4] = {u_lds[r0], u_lds[r0 + 1], u_lds[r0 + 2], u_lds[r0 + 3]};
            float t16[16];
#pragma unroll
            for (int c = 0; c < 16; ++c) {
                float t = 0.f;
#pragma unroll
                for (int k = 0; k < 4; ++k) t = fmaf(K[k * 16 + c], uu[k], t);
                t16[c] = t;
            }
#pragma unroll
            for (int c = 0; c < 16; ++c) {
                t16[c] += __shfl_xor(t16[c], 4);
                t16[c] += __shfl_xor(t16[c], 8);
                t16[c] += __shfl_xor(t16[c], 16);
                t16[c] += __shfl_xor(t16[c], 32);
            }
            const int w = tid >> 6, l = tid & 63;
            if (l < 4) {
#pragma unroll
                for (int c = 0; c < 16; ++c) t_acc[w][l + 4 * c] = t16[c];
            }
        }
        __syncthreads();
        if (tid < 64) {
            float t = 0.f;
#pragma unroll
            for (int w2 = 0; w2 < 16; ++w2) t += t_acc[w2][tid];
            float vc = v_lds[cur][tid];
            float beta = vc * t;
            float e = fabsf(beta - CVAL);
            v_lds[cur ^ 1][tid] = vc * CVAL / fmaxf(beta, TINY_);
            e = waveRedSum(e);
            if (tid == 0) sysstoref(&errpart[b], e);
        }
        __syncthreads();
        cur ^= 1;
    }

    const float* uEpi = ubuf + (((it & 1) ^ 1) << 10);
    float vv[16];
#pragma unroll
    for (int c = 0; c < 16; ++c) vv[c] = v_lds[vsel][ch + 4 * c];
    float uu[4];
#pragma unroll
    for (int k = 0; k < 4; ++k) uu[k] = sysloadf(&uEpi[r0 + k]);
    float4 mm4 = *(const float4*)(Mmin + r0);
    float mm[4] = {mm4.x, mm4.y, mm4.z, mm4.w};
    float lsum = 0.f;
#pragma unroll
    for (int k = 0; k < 4; ++k) {
        float* prow = Pbuf + (size_t)(r0 + k) * M_COLS + c0 + ch;
#pragma unroll
        for (int c = 0; c < 16; ++c) {
            float kv = K[k * 16 + c];
            float p = 0.f;
            if (kv > 0.f) {
                p = uu[k] * kv * vv[c];
                float m = mm[k] - __logf(kv) * INV_GAMMA;
                lsum = fmaf(p, m, lsum);
            }
            prow[4 * c] = p;
        }
    }
    lsum = waveRedSum(lsum);
    if ((tid & 63) == 0) red[tid >> 6] = lsum;
    __syncthreads();
    if (tid == 0) {
        float s = 0.f;
#pragma unroll
        for (int i = 0; i < 16; ++i) s += red[i];
        atomicAdd(out, s);
    }
}

extern "C" void kernel_launch(void* const* d_in, const int* in_sizes, int n_in,
                              void* d_out, int out_size, void* d_ws, size_t ws_size,
                              hipStream_t stream) {
    const float* x = (const float*)d_in[0];
    const float* y = (const float*)d_in[1];
    float* out = (float*)d_out;
    float* P = out + 1;
    float* ws = (float*)d_ws;
    float* sx   = ws;                        // 1024
    float* sy   = ws + 1024;                 // 16384
    float* Mmin = ws + 17408;                // 1024
    float* ubuf = ws + 18432;                // 2 x 1024
    unsigned* bar = (unsigned*)(ws + 20480); // 512 uints

    row_sqnorm<<<N_ROWS, 128, 0, stream>>>(x, sx);
    row_sqnorm<<<M_COLS, 128, 0, stream>>>(y, sy);
    init_state<<<4, 256, 0, stream>>>(ubuf, bar, out);
    gemm_dist_mfma<<<1024, 256, 0, stream>>>(x, y, sx, sy, P);
    row_min<<<N_ROWS, 256, 0, stream>>>(P, Mmin);
    {
        const float* Mminc = Mmin;
        void* args[] = {(void*)&Mminc, (void*)&ubuf, (void*)&out, (void*)&bar};
        hipLaunchCooperativeKernel((const void*)sinkhorn_reg, dim3(256), dim3(1024), args, 0, stream);
    }
}